// Round 8
// baseline (761.268 us; speedup 1.0000x reference)
//
#include <hip/hip_runtime.h>
#include <stdint.h>

// ---------------------------------------------------------------------------
// GAT bot detector, 2-layer, N=50000 E=800000 IN=256 HID=128 HEADS=4.
// Round 8: (1) persistent-wave work queue for agg1/agg2 (decouple waves from
// blocks; degree imbalance killed r7 occupancy at 37%); (2) attn coefficients
// fused into GEMM epilogues (GEMM1 col-tile == one head; GEMM2 covers full
// row) removing 2 dispatches + 64 MB re-read. Sync-staged GEMMs kept
// (global_load_lds proved racy in r2). Alpha fused in agg staging (r7).
// ---------------------------------------------------------------------------

typedef _Float16 f16;
typedef f16 f16x8 __attribute__((ext_vector_type(8)));
typedef f16 f16x4 __attribute__((ext_vector_type(4)));
typedef f16 f16x2 __attribute__((ext_vector_type(2)));
typedef float f32x4 __attribute__((ext_vector_type(4)));

#define AGG_BLOCKS 2048
#define AGG_WAVES (AGG_BLOCKS * 4)
#define B1 2
#define B2 4

// --------------------------- CSR construction ------------------------------

// Also re-initializes the agg work-queue counters every launch (graph-safe).
__global__ void detect_i64_kernel(const int* __restrict__ ei, int* __restrict__ flag,
                                  int* __restrict__ ctrs) {
  if (threadIdx.x == 0 && blockIdx.x == 0) {
    int nz = 0;
    for (int i = 0; i < 256; ++i) nz |= ei[2 * i + 1];
    *flag = (nz == 0) ? 1 : 0;
    ctrs[0] = AGG_WAVES * B1;  // agg1 static prefix
    ctrs[1] = AGG_WAVES * B2;  // agg2 static prefix
  }
}

__global__ void hist_kernel(const int* __restrict__ ei, int E, int N,
                            const int* __restrict__ flagp, int* __restrict__ deg) {
  int idx = blockIdx.x * blockDim.x + threadIdx.x;
  int EA = E + N;
  if (idx >= EA) return;
  int dst;
  if (idx < E) {
    dst = (*flagp) ? ei[2 * ((size_t)E + idx)] : ei[(size_t)E + idx];
  } else {
    dst = idx - E;  // self loop
  }
  if ((unsigned)dst >= (unsigned)N) return;
  atomicAdd(&deg[dst], 1);
}

// 3-phase scan: per-block inclusive -> block-sums scan -> fixup.
__global__ __launch_bounds__(256) void scan1_kernel(const int* __restrict__ deg,
                                                    int* __restrict__ tmp,
                                                    int* __restrict__ bsum, int n) {
  __shared__ int sd[256];
  const int t = threadIdx.x;
  const int i = blockIdx.x * 256 + t;
  int x = (i < n) ? deg[i] : 0;
  sd[t] = x;
  __syncthreads();
  for (int off = 1; off < 256; off <<= 1) {
    int v = (t >= off) ? sd[t - off] : 0;
    __syncthreads();
    sd[t] += v;
    __syncthreads();
  }
  if (i < n) tmp[i] = sd[t];
  if (t == 255) bsum[blockIdx.x] = sd[255];
}

__global__ __launch_bounds__(256) void scan2_kernel(const int* __restrict__ bsum,
                                                    int* __restrict__ boff, int nb) {
  __shared__ int sd[256];
  const int t = threadIdx.x;
  int x = (t < nb) ? bsum[t] : 0;
  sd[t] = x;
  __syncthreads();
  for (int off = 1; off < 256; off <<= 1) {
    int v = (t >= off) ? sd[t - off] : 0;
    __syncthreads();
    sd[t] += v;
    __syncthreads();
  }
  if (t < nb) boff[t] = sd[t] - x;  // exclusive
}

__global__ void scan3_kernel(const int* __restrict__ deg, const int* __restrict__ tmp,
                             const int* __restrict__ boff, int* __restrict__ row_ptr,
                             int* __restrict__ cursor, int n) {
  int i = blockIdx.x * 256 + threadIdx.x;
  if (i >= n) return;
  int g = tmp[i] + boff[i >> 8];
  row_ptr[i + 1] = g;
  cursor[i] = g - deg[i];
  if (i == 0) row_ptr[0] = 0;
}

__global__ void scatter_kernel(const int* __restrict__ ei, int E, int N,
                               const int* __restrict__ flagp,
                               int* __restrict__ cursor, int* __restrict__ csr) {
  int idx = blockIdx.x * blockDim.x + threadIdx.x;
  int EA = E + N;
  if (idx >= EA) return;
  int src, dst;
  if (idx < E) {
    if (*flagp) { src = ei[2 * (size_t)idx]; dst = ei[2 * ((size_t)E + idx)]; }
    else        { src = ei[(size_t)idx];     dst = ei[(size_t)E + idx]; }
  } else {
    src = dst = idx - E;
  }
  if ((unsigned)dst >= (unsigned)N || (unsigned)src >= (unsigned)N) return;
  int pos = atomicAdd(&cursor[dst], 1);
  csr[pos] = src;
}

// --------------------------- f32 -> f16 convert ----------------------------
__global__ void cvt_f16_kernel(const float* __restrict__ src, f16* __restrict__ dst,
                               int srcRows, int dstRows, int cols, int gshift) {
  int idx = blockIdx.x * blockDim.x + threadIdx.x;
  int total = dstRows << gshift;
  if (idx >= total) return;
  int row = idx >> gshift;
  int col = (idx & ((1 << gshift) - 1)) * 4;
  float4 v = make_float4(0.f, 0.f, 0.f, 0.f);
  if (row < srcRows) v = *(const float4*)&src[(size_t)row * cols + col];
  f16x4 o = {(f16)v.x, (f16)v.y, (f16)v.z, (f16)v.w};
  *(f16x4*)&dst[(size_t)row * cols + col] = o;
}

// --------------------- GEMM1: A f32 (x), B f16 (W1 f16) --------------------
// C[M,512] = x * W1^T; pad rows clamped to N-1 (outputs unused). f32->f16
// conversion in-register during staging. Column tile (128) == one head, so
// the attn coefficients aS1/aD1 for this head are reduced from acc in the
// epilogue (intra-16-lane shfl over cols, LDS cross-wave combine).
__global__ __launch_bounds__(256) void gemm1_kernel(
    const float* __restrict__ A, const f16* __restrict__ Bm, f16* __restrict__ C,
    const float* __restrict__ attS, const float* __restrict__ attD,
    float* __restrict__ aS, float* __restrict__ aD,
    int K, int Ncols, int Nrows) {
  __shared__ f16 lA[128 * 32];
  __shared__ f16 lB[128 * 32];
  const int tid = threadIdx.x;
  const int w = tid >> 6, lane = tid & 63;
  const int wm = w >> 1, wn = w & 1;
  const int rowBase = blockIdx.y * 128;
  const int colBase = blockIdx.x * 128;
  const int lrow = lane & 15, lk = lane >> 4;
  f32x4 acc[4][4];
#pragma unroll
  for (int i = 0; i < 4; ++i)
#pragma unroll
    for (int j = 0; j < 4; ++j) acc[i][j] = (f32x4){0.f, 0.f, 0.f, 0.f};

  for (int kv = 0; kv < K; kv += 32) {
    f16x8 stA[2], stB[2];
#pragma unroll
    for (int s = 0; s < 2; ++s) {
      int q = s * 256 + tid;
      int r = q >> 2;
      int cs = (q & 3) ^ ((r >> 1) & 3);
      int row = rowBase + r;
      if (row >= Nrows) row = Nrows - 1;  // clamp: pad-row outputs unused
      const float4 v0 = *(const float4*)(A + (size_t)row * K + kv + cs * 8);
      const float4 v1 = *(const float4*)(A + (size_t)row * K + kv + cs * 8 + 4);
      f16x8 o = {(f16)v0.x, (f16)v0.y, (f16)v0.z, (f16)v0.w,
                 (f16)v1.x, (f16)v1.y, (f16)v1.z, (f16)v1.w};
      stA[s] = o;
    }
#pragma unroll
    for (int s = 0; s < 2; ++s) {
      int q = s * 256 + tid;
      int r = q >> 2;
      int cs = (q & 3) ^ ((r >> 1) & 3);
      stB[s] = *(const f16x8*)(Bm + (size_t)(colBase + r) * K + kv + cs * 8);
    }
#pragma unroll
    for (int s = 0; s < 2; ++s) *(f16x8*)&lA[(size_t)(s * 256 + tid) * 8] = stA[s];
#pragma unroll
    for (int s = 0; s < 2; ++s) *(f16x8*)&lB[(size_t)(s * 256 + tid) * 8] = stB[s];
    __syncthreads();
    f16x8 aF[4], bF[4];
#pragma unroll
    for (int i = 0; i < 4; ++i) {
      int ra = wm * 64 + i * 16 + lrow;
      aF[i] = *(const f16x8*)&lA[(ra * 4 + (lk ^ ((ra >> 1) & 3))) * 8];
      int rb = wn * 64 + i * 16 + lrow;
      bF[i] = *(const f16x8*)&lB[(rb * 4 + (lk ^ ((rb >> 1) & 3))) * 8];
    }
#pragma unroll
    for (int i = 0; i < 4; ++i)
#pragma unroll
      for (int j = 0; j < 4; ++j)
        acc[i][j] = __builtin_amdgcn_mfma_f32_16x16x32_f16(aF[i], bF[j], acc[i][j], 0, 0, 0);
    __syncthreads();
  }
  // C store (layout: col = lane&15, row = (lane>>4)*4 + reg)
#pragma unroll
  for (int i = 0; i < 4; ++i) {
    int row0 = rowBase + wm * 64 + i * 16 + lk * 4;
#pragma unroll
    for (int j = 0; j < 4; ++j) {
      int col = colBase + wn * 64 + j * 16 + lrow;
#pragma unroll
      for (int rr = 0; rr < 4; ++rr)
        C[(size_t)(row0 + rr) * Ncols + col] = (f16)acc[i][j][rr];
    }
  }
  // Fused attn epilogue: this block covers head h = colBase/128 fully.
  const int h = colBase >> 7;
  float sv[4], dv[4];
#pragma unroll
  for (int j = 0; j < 4; ++j) {
    int cl = wn * 64 + j * 16 + lrow;
    sv[j] = attS[h * 128 + cl];
    dv[j] = attD[h * 128 + cl];
  }
  float* sred = (float*)lA;  // [wn][128 rows][2] = 2 KB, LDS free after loop
#pragma unroll
  for (int i = 0; i < 4; ++i) {
#pragma unroll
    for (int rr = 0; rr < 4; ++rr) {
      float ps = 0.f, pd = 0.f;
#pragma unroll
      for (int j = 0; j < 4; ++j) {
        ps = fmaf(acc[i][j][rr], sv[j], ps);
        pd = fmaf(acc[i][j][rr], dv[j], pd);
      }
#pragma unroll
      for (int off = 1; off < 16; off <<= 1) {
        ps += __shfl_xor(ps, off);
        pd += __shfl_xor(pd, off);
      }
      if (lrow == 0) {
        int rloc = wm * 64 + i * 16 + lk * 4 + rr;
        sred[(wn * 128 + rloc) * 2 + 0] = ps;
        sred[(wn * 128 + rloc) * 2 + 1] = pd;
      }
    }
  }
  __syncthreads();
  if (tid < 128) {
    int row = rowBase + tid;
    if (row < Nrows) {
      aS[(size_t)row * 4 + h] = sred[tid * 2] + sred[(128 + tid) * 2];
      aD[(size_t)row * 4 + h] = sred[tid * 2 + 1] + sred[(128 + tid) * 2 + 1];
    }
  }
}

// ------------------- GEMM2 (BM=64, TPB=128) + fused attn2 ------------------
// C[M,128] = A2 * W2^T; block covers the full 128-col row -> aS2/aD2 fused.
__global__ __launch_bounds__(128) void gemm2_kernel(
    const f16* __restrict__ A, const f16* __restrict__ Bm, f16* __restrict__ C,
    const float* __restrict__ attS, const float* __restrict__ attD,
    float* __restrict__ aS, float* __restrict__ aD,
    int K, int Ncols, int Nrows) {
  __shared__ f16 lA[64 * 32];
  __shared__ f16 lB[128 * 32];
  const int tid = threadIdx.x;
  const int w = tid >> 6, lane = tid & 63;
  const int wn = w & 1;  // wm = 0
  const int rowBase = blockIdx.y * 64;
  const int lrow = lane & 15, lk = lane >> 4;
  f32x4 acc[4][4];
#pragma unroll
  for (int i = 0; i < 4; ++i)
#pragma unroll
    for (int j = 0; j < 4; ++j) acc[i][j] = (f32x4){0.f, 0.f, 0.f, 0.f};

  for (int kv = 0; kv < K; kv += 32) {
    f16x8 stA[2], stB[4];
#pragma unroll
    for (int s = 0; s < 2; ++s) {
      int q = s * 128 + tid;
      int r = q >> 2;
      int cs = (q & 3) ^ ((r >> 1) & 3);
      stA[s] = *(const f16x8*)(A + (size_t)(rowBase + r) * K + kv + cs * 8);
    }
#pragma unroll
    for (int s = 0; s < 4; ++s) {
      int q = s * 128 + tid;
      int r = q >> 2;
      int cs = (q & 3) ^ ((r >> 1) & 3);
      stB[s] = *(const f16x8*)(Bm + (size_t)r * K + kv + cs * 8);
    }
#pragma unroll
    for (int s = 0; s < 2; ++s) *(f16x8*)&lA[(size_t)(s * 128 + tid) * 8] = stA[s];
#pragma unroll
    for (int s = 0; s < 4; ++s) *(f16x8*)&lB[(size_t)(s * 128 + tid) * 8] = stB[s];
    __syncthreads();
    f16x8 aF[4], bF[4];
#pragma unroll
    for (int i = 0; i < 4; ++i) {
      int ra = i * 16 + lrow;
      aF[i] = *(const f16x8*)&lA[(ra * 4 + (lk ^ ((ra >> 1) & 3))) * 8];
      int rb = wn * 64 + i * 16 + lrow;
      bF[i] = *(const f16x8*)&lB[(rb * 4 + (lk ^ ((rb >> 1) & 3))) * 8];
    }
#pragma unroll
    for (int i = 0; i < 4; ++i)
#pragma unroll
      for (int j = 0; j < 4; ++j)
        acc[i][j] = __builtin_amdgcn_mfma_f32_16x16x32_f16(aF[i], bF[j], acc[i][j], 0, 0, 0);
    __syncthreads();
  }
#pragma unroll
  for (int i = 0; i < 4; ++i) {
    int row0 = rowBase + i * 16 + lk * 4;
#pragma unroll
    for (int j = 0; j < 4; ++j) {
      int col = wn * 64 + j * 16 + lrow;
#pragma unroll
      for (int rr = 0; rr < 4; ++rr)
        C[(size_t)(row0 + rr) * Ncols + col] = (f16)acc[i][j][rr];
    }
  }
  // Fused attn2 epilogue (H = 1)
  float sv[4], dv[4];
#pragma unroll
  for (int j = 0; j < 4; ++j) {
    int cl = wn * 64 + j * 16 + lrow;
    sv[j] = attS[cl];
    dv[j] = attD[cl];
  }
  float* sred = (float*)lA;  // [wn][64][2] = 1 KB
#pragma unroll
  for (int i = 0; i < 4; ++i) {
#pragma unroll
    for (int rr = 0; rr < 4; ++rr) {
      float ps = 0.f, pd = 0.f;
#pragma unroll
      for (int j = 0; j < 4; ++j) {
        ps = fmaf(acc[i][j][rr], sv[j], ps);
        pd = fmaf(acc[i][j][rr], dv[j], pd);
      }
#pragma unroll
      for (int off = 1; off < 16; off <<= 1) {
        ps += __shfl_xor(ps, off);
        pd += __shfl_xor(pd, off);
      }
      if (lrow == 0) {
        int rloc = i * 16 + lk * 4 + rr;
        sred[(wn * 64 + rloc) * 2 + 0] = ps;
        sred[(wn * 64 + rloc) * 2 + 1] = pd;
      }
    }
  }
  __syncthreads();
  if (tid < 64) {
    int row = rowBase + tid;
    if (row < Nrows) {
      aS[row] = sred[tid * 2] + sred[(64 + tid) * 2];
      aD[row] = sred[tid * 2 + 1] + sred[(64 + tid) * 2 + 1];
    }
  }
}

// --------------------- layer-1 aggregation (queue) -------------------------
// Persistent waves; each wave independently claims B1 dsts (static first
// batch, then atomic queue) -> no block-level degree-imbalance coupling.
// Per dst: stage (src, alpha4) to wave-private LDS (alpha fused from aS/aD,
// L2-hot), branch-free 8-deep unrolled f16x8 row gathers, normalize+bias+ELU
// in epilogue.
__global__ __launch_bounds__(256) void agg1_kernel(
    const int* __restrict__ row_ptr, const int* __restrict__ csr,
    const float* __restrict__ aS, const float* __restrict__ aD,
    const f16* __restrict__ xw, const float* __restrict__ bias,
    f16* __restrict__ A2, int* __restrict__ ctr, int n) {
  __shared__ float4 lal[4][64];
  __shared__ int lsrc[4][64];
  const int wv = threadIdx.x >> 6, lane = threadIdx.x & 63;
  const int wid = blockIdx.x * 4 + wv;
  const int hh = lane >> 4;
  const f16* __restrict__ xcol = xw + lane * 8;
  const float* __restrict__ lalf = (const float*)&lal[wv][0];
  const int c = lane * 8;
  const float4 b0 = *(const float4*)&bias[c];
  const float4 b1 = *(const float4*)&bias[c + 4];
  const float bb[8] = {b0.x, b0.y, b0.z, b0.w, b1.x, b1.y, b1.z, b1.w};

  int nd = wid * B1;
  while (nd < n) {
    const int lim = min(nd + B1, n);
    for (int dst = nd; dst < lim; ++dst) {
      const int beg = row_ptr[dst], end = row_ptr[dst + 1];
      const float4 ad4 = *(const float4*)&aD[(size_t)dst * 4];
      f32x4 den4 = {0.f, 0.f, 0.f, 0.f};
      float acc[8] = {0.f, 0.f, 0.f, 0.f, 0.f, 0.f, 0.f, 0.f};
      for (int base = beg; base < end; base += 64) {
        int i = base + lane;
        int s = 0;
        float4 a4 = make_float4(0.f, 0.f, 0.f, 0.f);
        if (i < end) {
          s = csr[i];
          const float4 as4 = *(const float4*)&aS[(size_t)s * 4];
          float x0 = as4.x + ad4.x; x0 = (x0 > 0.f) ? x0 : 0.2f * x0; a4.x = __expf(x0);
          float x1 = as4.y + ad4.y; x1 = (x1 > 0.f) ? x1 : 0.2f * x1; a4.y = __expf(x1);
          float x2 = as4.z + ad4.z; x2 = (x2 > 0.f) ? x2 : 0.2f * x2; a4.z = __expf(x2);
          float x3 = as4.w + ad4.w; x3 = (x3 > 0.f) ? x3 : 0.2f * x3; a4.w = __expf(x3);
        }
        den4[0] += a4.x; den4[1] += a4.y; den4[2] += a4.z; den4[3] += a4.w;
        lsrc[wv][lane] = s;
        lal[wv][lane] = a4;
        asm volatile("s_waitcnt lgkmcnt(0)" ::: "memory");
        const int m = min(64, end - base);
        const int jm = (m + 7) & ~7;  // pad slots: alpha=0, src=0
        for (int j = 0; j < jm; j += 8) {
          int sj[8];
          float aj[8];
          f16x8 v[8];
#pragma unroll
          for (int k = 0; k < 8; ++k) {
            sj[k] = lsrc[wv][j + k];
            aj[k] = lalf[(j + k) * 4 + hh];
          }
#pragma unroll
          for (int k = 0; k < 8; ++k) v[k] = *(const f16x8*)&xcol[(size_t)sj[k] * 512];
#pragma unroll
          for (int k = 0; k < 8; ++k)
#pragma unroll
            for (int q = 0; q < 8; ++q) acc[q] = fmaf(aj[k], (float)v[k][q], acc[q]);
        }
      }
#pragma unroll
      for (int off = 32; off; off >>= 1) {
#pragma unroll
        for (int k = 0; k < 4; ++k) den4[k] += __shfl_xor(den4[k], off);
      }
      float dh = (hh == 0) ? den4[0] : (hh == 1) ? den4[1] : (hh == 2) ? den4[2] : den4[3];
      const float inv = 1.f / dh;
      f16x8 o;
#pragma unroll
      for (int q = 0; q < 8; ++q) {
        float vv = acc[q] * inv + bb[q];
        vv = (vv > 0.f) ? vv : (__expf(vv) - 1.f);
        o[q] = (f16)vv;
      }
      *(f16x8*)&A2[(size_t)dst * 512 + c] = o;
    }
    if (lane == 0) nd = atomicAdd(ctr, B1);
    nd = __shfl(nd, 0);
  }
}

// ------------- layer-2 aggregation + ELU + classifier (queue) --------------
__global__ __launch_bounds__(256) void agg2_kernel(
    const int* __restrict__ row_ptr, const int* __restrict__ csr,
    const float* __restrict__ aS, const float* __restrict__ aD,
    const f16* __restrict__ xw2, const float* __restrict__ b2,
    const float* __restrict__ Wc, const float* __restrict__ bc,
    float* __restrict__ out, int* __restrict__ ctr, int n) {
  __shared__ float2 led[4][64];
  const int wv = threadIdx.x >> 6, lane = threadIdx.x & 63;
  const int wid = blockIdx.x * 4 + wv;
  const int half = lane >> 5, lc = lane & 31;
  const f16* __restrict__ xrow = xw2 + lc * 4;
  const int c = lc * 4;
  const float4 bb = *(const float4*)&b2[c];
  const float4 w0 = *(const float4*)&Wc[c];
  const float4 w1 = *(const float4*)&Wc[128 + c];
  const float bv[4] = {bb.x, bb.y, bb.z, bb.w};
  const float w0v[4] = {w0.x, w0.y, w0.z, w0.w};
  const float w1v[4] = {w1.x, w1.y, w1.z, w1.w};

  int nd = wid * B2;
  while (nd < n) {
    const int lim = min(nd + B2, n);
    for (int dst = nd; dst < lim; ++dst) {
      const int beg = row_ptr[dst], end = row_ptr[dst + 1];
      const float ad = aD[dst];
      float den = 0.f;
      float acc[4] = {0.f, 0.f, 0.f, 0.f};
      for (int base = beg; base < end; base += 64) {
        int i = base + lane;
        float2 pa = make_float2(__int_as_float(0), 0.f);
        if (i < end) {
          int s = csr[i];
          float x = aS[s] + ad;
          x = (x > 0.f) ? x : 0.2f * x;
          pa = make_float2(__int_as_float(s), __expf(x));
        }
        den += pa.y;
        led[wv][lane] = pa;
        asm volatile("s_waitcnt lgkmcnt(0)" ::: "memory");
        const int m = min(64, end - base);
        const int pr = (((m + 1) >> 1) + 7) & ~7;  // pad pairs: alpha=0, src=0
        for (int p = 0; p < pr; p += 8) {
          int sj[8];
          float aj[8];
          f16x4 v[8];
#pragma unroll
          for (int k = 0; k < 8; ++k) {
            float2 q = led[wv][(p + k) * 2 + half];
            sj[k] = __float_as_int(q.x);
            aj[k] = q.y;
          }
#pragma unroll
          for (int k = 0; k < 8; ++k) v[k] = *(const f16x4*)&xrow[(size_t)sj[k] * 128];
#pragma unroll
          for (int k = 0; k < 8; ++k) {
            acc[0] = fmaf(aj[k], (float)v[k][0], acc[0]);
            acc[1] = fmaf(aj[k], (float)v[k][1], acc[1]);
            acc[2] = fmaf(aj[k], (float)v[k][2], acc[2]);
            acc[3] = fmaf(aj[k], (float)v[k][3], acc[3]);
          }
        }
      }
      float d2 = den;
#pragma unroll
      for (int off = 32; off; off >>= 1) d2 += __shfl_xor(d2, off);
      const float inv = 1.f / d2;
      float a0 = acc[0] + __shfl_xor(acc[0], 32);
      float a1 = acc[1] + __shfl_xor(acc[1], 32);
      float a2 = acc[2] + __shfl_xor(acc[2], 32);
      float a3 = acc[3] + __shfl_xor(acc[3], 32);
      const float av[4] = {a0, a1, a2, a3};
      float l0 = 0.f, l1 = 0.f;
#pragma unroll
      for (int k = 0; k < 4; ++k) {
        float vv = av[k] * inv + bv[k];
        vv = (vv > 0.f) ? vv : (__expf(vv) - 1.f);
        l0 = fmaf(vv, w0v[k], l0);
        l1 = fmaf(vv, w1v[k], l1);
      }
#pragma unroll
      for (int off = 16; off; off >>= 1) {
        l0 += __shfl_xor(l0, off);
        l1 += __shfl_xor(l1, off);
      }
      if (lane == 0) {
        out[dst * 2] = l0 + bc[0];
        out[dst * 2 + 1] = l1 + bc[1];
      }
    }
    if (lane == 0) nd = atomicAdd(ctr, B2);
    nd = __shfl(nd, 0);
  }
}

// ---------------------------------------------------------------------------

extern "C" void kernel_launch(void* const* d_in, const int* in_sizes, int n_in,
                              void* d_out, int out_size, void* d_ws, size_t ws_size,
                              hipStream_t stream) {
  const float* x     = (const float*)d_in[0];
  const int*   ei    = (const int*)d_in[1];
  const float* W1    = (const float*)d_in[2];
  const float* att1s = (const float*)d_in[3];
  const float* att1d = (const float*)d_in[4];
  const float* b1    = (const float*)d_in[5];
  const float* W2    = (const float*)d_in[6];
  const float* att2s = (const float*)d_in[7];
  const float* att2d = (const float*)d_in[8];
  const float* b2    = (const float*)d_in[9];
  const float* Wc    = (const float*)d_in[10];
  const float* bc    = (const float*)d_in[11];
  float* out = (float*)d_out;

  const int N = in_sizes[0] / 256;
  const int E = in_sizes[1] / 2;
  const int EA = E + N;
  const int Mpad = (N + 127) & ~127;
  const int NB = (N + 255) / 256;
  const int EB = (EA + 255) / 256;

  char* base = (char*)d_ws;
  size_t off = 0;
  auto alloc = [&](size_t bytes) -> char* {
    char* p = base + off;
    off = (off + bytes + 255) & ~(size_t)255;
    return p;
  };
  f16* B1f  = (f16*)alloc((size_t)512 * 256 * sizeof(f16));    // W1 f16
  f16* xw1h = (f16*)alloc((size_t)Mpad * 512 * sizeof(f16));   // layer1 pre-agg
  f16* A2   = (f16*)alloc((size_t)Mpad * 512 * sizeof(f16));   // h = elu(agg1)
  f16* B2f  = (f16*)alloc((size_t)128 * 512 * sizeof(f16));    // W2 f16
  f16* xw2h = (f16*)alloc((size_t)Mpad * 128 * sizeof(f16));   // layer2 pre-agg
  float* aS1 = (float*)alloc((size_t)N * 4 * sizeof(float));
  float* aD1 = (float*)alloc((size_t)N * 4 * sizeof(float));
  float* aS2 = (float*)alloc((size_t)N * sizeof(float));
  float* aD2 = (float*)alloc((size_t)N * sizeof(float));
  int* deg     = (int*)alloc((size_t)N * sizeof(int));
  int* row_ptr = (int*)alloc((size_t)(N + 1) * sizeof(int));
  int* cursor  = (int*)alloc((size_t)N * sizeof(int));
  int* csr     = (int*)alloc((size_t)EA * sizeof(int));
  int* tmp     = (int*)alloc((size_t)N * sizeof(int));
  int* bsum    = (int*)alloc((size_t)NB * sizeof(int));
  int* boff    = (int*)alloc((size_t)NB * sizeof(int));
  int* flag    = (int*)alloc(256);
  int* ctrs    = (int*)alloc(256);
  (void)n_in; (void)out_size; (void)ws_size;

  hipMemsetAsync(deg, 0, (size_t)N * sizeof(int), stream);
  if (Mpad > N)  // zero A2 pad rows so GEMM2 pad outputs stay finite
    hipMemsetAsync(A2 + (size_t)N * 512, 0, (size_t)(Mpad - N) * 512 * sizeof(f16), stream);

  detect_i64_kernel<<<1, 64, 0, stream>>>(ei, flag, ctrs);
  hist_kernel<<<EB, 256, 0, stream>>>(ei, E, N, flag, deg);
  scan1_kernel<<<NB, 256, 0, stream>>>(deg, tmp, bsum, N);
  scan2_kernel<<<1, 256, 0, stream>>>(bsum, boff, NB);
  scan3_kernel<<<NB, 256, 0, stream>>>(deg, tmp, boff, row_ptr, cursor, N);
  scatter_kernel<<<EB, 256, 0, stream>>>(ei, E, N, flag, cursor, csr);

  cvt_f16_kernel<<<(512 * 64 + 255) / 256, 256, 0, stream>>>(W1, B1f, 512, 512, 256, 6);
  cvt_f16_kernel<<<(128 * 128 + 255) / 256, 256, 0, stream>>>(W2, B2f, 128, 128, 512, 7);

  dim3 g1(4, Mpad / 128);
  gemm1_kernel<<<g1, 256, 0, stream>>>(x, B1f, xw1h, att1s, att1d, aS1, aD1, 256, 512, N);
  agg1_kernel<<<AGG_BLOCKS, 256, 0, stream>>>(row_ptr, csr, aS1, aD1, xw1h, b1, A2, &ctrs[0], N);

  dim3 g2(1, Mpad / 64);
  gemm2_kernel<<<g2, 128, 0, stream>>>(A2, B2f, xw2h, att2s, att2d, aS2, aD2, 512, 128, N);
  agg2_kernel<<<AGG_BLOCKS, 256, 0, stream>>>(row_ptr, csr, aS2, aD2, xw2h, b2, Wc, bc, out, &ctrs[1], N);
}

// Round 9
// 430.226 us; speedup vs baseline: 1.7695x; 1.7695x over previous
//
#include <hip/hip_runtime.h>
#include <stdint.h>

// ---------------------------------------------------------------------------
// GAT bot detector, 2-layer, N=50000 E=800000 IN=256 HID=128 HEADS=4.
// Round 9: x-space aggregation for layer 1 (GAT is linear in x; attn coefs
// are rank-1: aS = x @ (W1^T att_src)). agg1 gathers 512B x-rows (was 1KB
// xw rows); GEMM1 moves after aggregation with fused bias+ELU. Static wave->
// dst mapping restored (r8's single-counter queue serialized on atomics).
// Sync-staged GEMMs kept (global_load_lds proved racy in r2).
// ---------------------------------------------------------------------------

typedef _Float16 f16;
typedef f16 f16x8 __attribute__((ext_vector_type(8)));
typedef f16 f16x4 __attribute__((ext_vector_type(4)));
typedef f16 f16x2 __attribute__((ext_vector_type(2)));
typedef float f32x4 __attribute__((ext_vector_type(4)));

// --------------------------- CSR construction ------------------------------

__global__ void detect_i64_kernel(const int* __restrict__ ei, int* __restrict__ flag) {
  if (threadIdx.x == 0 && blockIdx.x == 0) {
    int nz = 0;
    for (int i = 0; i < 256; ++i) nz |= ei[2 * i + 1];
    *flag = (nz == 0) ? 1 : 0;
  }
}

__global__ void hist_kernel(const int* __restrict__ ei, int E, int N,
                            const int* __restrict__ flagp, int* __restrict__ deg) {
  int idx = blockIdx.x * blockDim.x + threadIdx.x;
  int EA = E + N;
  if (idx >= EA) return;
  int dst;
  if (idx < E) {
    dst = (*flagp) ? ei[2 * ((size_t)E + idx)] : ei[(size_t)E + idx];
  } else {
    dst = idx - E;  // self loop
  }
  if ((unsigned)dst >= (unsigned)N) return;
  atomicAdd(&deg[dst], 1);
}

// 3-phase scan: per-block inclusive -> block-sums scan -> fixup.
__global__ __launch_bounds__(256) void scan1_kernel(const int* __restrict__ deg,
                                                    int* __restrict__ tmp,
                                                    int* __restrict__ bsum, int n) {
  __shared__ int sd[256];
  const int t = threadIdx.x;
  const int i = blockIdx.x * 256 + t;
  int x = (i < n) ? deg[i] : 0;
  sd[t] = x;
  __syncthreads();
  for (int off = 1; off < 256; off <<= 1) {
    int v = (t >= off) ? sd[t - off] : 0;
    __syncthreads();
    sd[t] += v;
    __syncthreads();
  }
  if (i < n) tmp[i] = sd[t];
  if (t == 255) bsum[blockIdx.x] = sd[255];
}

__global__ __launch_bounds__(256) void scan2_kernel(const int* __restrict__ bsum,
                                                    int* __restrict__ boff, int nb) {
  __shared__ int sd[256];
  const int t = threadIdx.x;
  int x = (t < nb) ? bsum[t] : 0;
  sd[t] = x;
  __syncthreads();
  for (int off = 1; off < 256; off <<= 1) {
    int v = (t >= off) ? sd[t - off] : 0;
    __syncthreads();
    sd[t] += v;
    __syncthreads();
  }
  if (t < nb) boff[t] = sd[t] - x;  // exclusive
}

__global__ void scan3_kernel(const int* __restrict__ deg, const int* __restrict__ tmp,
                             const int* __restrict__ boff, int* __restrict__ row_ptr,
                             int* __restrict__ cursor, int n) {
  int i = blockIdx.x * 256 + threadIdx.x;
  if (i >= n) return;
  int g = tmp[i] + boff[i >> 8];
  row_ptr[i + 1] = g;
  cursor[i] = g - deg[i];
  if (i == 0) row_ptr[0] = 0;
}

__global__ void scatter_kernel(const int* __restrict__ ei, int E, int N,
                               const int* __restrict__ flagp,
                               int* __restrict__ cursor, int* __restrict__ csr) {
  int idx = blockIdx.x * blockDim.x + threadIdx.x;
  int EA = E + N;
  if (idx >= EA) return;
  int src, dst;
  if (idx < E) {
    if (*flagp) { src = ei[2 * (size_t)idx]; dst = ei[2 * ((size_t)E + idx)]; }
    else        { src = ei[(size_t)idx];     dst = ei[(size_t)E + idx]; }
  } else {
    src = dst = idx - E;
  }
  if ((unsigned)dst >= (unsigned)N || (unsigned)src >= (unsigned)N) return;
  int pos = atomicAdd(&cursor[dst], 1);
  csr[pos] = src;
}

// --------------------------- f32 -> f16 convert ----------------------------
__global__ void cvt_f16_kernel(const float* __restrict__ src, f16* __restrict__ dst,
                               int srcRows, int dstRows, int cols, int gshift) {
  int idx = blockIdx.x * blockDim.x + threadIdx.x;
  int total = dstRows << gshift;
  if (idx >= total) return;
  int row = idx >> gshift;
  int col = (idx & ((1 << gshift) - 1)) * 4;
  float4 v = make_float4(0.f, 0.f, 0.f, 0.f);
  if (row < srcRows) v = *(const float4*)&src[(size_t)row * cols + col];
  f16x4 o = {(f16)v.x, (f16)v.y, (f16)v.z, (f16)v.w};
  *(f16x4*)&dst[(size_t)row * cols + col] = o;
}

// --------------- rank-1 attention projection: attW[c][8] -------------------
// attW[c][h*2+0] = sum_k W1[h*128+k, c] * att1s[h,k]; +1 -> att1d.
__global__ void attw_kernel(const float* __restrict__ W1, const float* __restrict__ s1,
                            const float* __restrict__ d1, float* __restrict__ attW) {
  const int h = blockIdx.x;
  const int c = threadIdx.x;
  float ps = 0.f, pd = 0.f;
  for (int k = 0; k < 128; ++k) {
    float w = W1[(size_t)(h * 128 + k) * 256 + c];
    ps = fmaf(w, s1[h * 128 + k], ps);
    pd = fmaf(w, d1[h * 128 + k], pd);
  }
  attW[c * 8 + h * 2] = ps;
  attW[c * 8 + h * 2 + 1] = pd;
}

// --------- fused x->f16 convert + per-node attn coefs (aSD1) ---------------
// wave per row: xf16 row out + aS1/aD1 (4 heads) via rank-1 attW.
__global__ __launch_bounds__(256) void cvtx_kernel(
    const float* __restrict__ x, const float* __restrict__ attW,
    f16* __restrict__ xf, float* __restrict__ aS, float* __restrict__ aD, int n) {
  __shared__ float w[256 * 8];
  for (int t = threadIdx.x; t < 2048; t += 256) w[t] = attW[t];
  __syncthreads();
  const int wv = threadIdx.x >> 6, lane = threadIdx.x & 63;
  const int row = blockIdx.x * 4 + wv;
  if (row >= n) return;
  const float4 v = *(const float4*)&x[(size_t)row * 256 + lane * 4];
  f16x4 o = {(f16)v.x, (f16)v.y, (f16)v.z, (f16)v.w};
  *(f16x4*)&xf[(size_t)row * 256 + lane * 4] = o;
  float p[8];
#pragma unroll
  for (int j = 0; j < 8; ++j) {
    p[j] = v.x * w[(lane * 4 + 0) * 8 + j] + v.y * w[(lane * 4 + 1) * 8 + j] +
           v.z * w[(lane * 4 + 2) * 8 + j] + v.w * w[(lane * 4 + 3) * 8 + j];
  }
#pragma unroll
  for (int off = 32; off; off >>= 1)
#pragma unroll
    for (int j = 0; j < 8; ++j) p[j] += __shfl_xor(p[j], off);
  if (lane == 0) {
#pragma unroll
    for (int h = 0; h < 4; ++h) {
      aS[(size_t)row * 4 + h] = p[h * 2];
      aD[(size_t)row * 4 + h] = p[h * 2 + 1];
    }
  }
}

// ------------------- layer-1 x-space aggregation (per dst) -----------------
// One wave per dst (static map). Staging per 64 edges: csr + aS1 gather ->
// alpha4 in-register -> wave-private LDS. Main loop: branch-free 8-deep
// unroll; lane owns 4 x-cols (f16x4 8B gather); 16 fma (4 heads x 4 cols).
// Epilogue: normalize per head, write aggX[dst, h*256 + cols] f16.
__global__ __launch_bounds__(256) void agg1_kernel(
    const int* __restrict__ row_ptr, const int* __restrict__ csr,
    const float* __restrict__ aS, const float* __restrict__ aD,
    const f16* __restrict__ xf, f16* __restrict__ aggX, int n) {
  __shared__ float4 lal[4][64];
  __shared__ int lsrc[4][64];
  const int wv = threadIdx.x >> 6, lane = threadIdx.x & 63;
  const int dst = blockIdx.x * 4 + wv;
  if (dst >= n) return;
  const int beg = row_ptr[dst], end = row_ptr[dst + 1];
  const float4 ad4 = *(const float4*)&aD[(size_t)dst * 4];
  f32x4 den4 = {0.f, 0.f, 0.f, 0.f};
  float acc[16];
#pragma unroll
  for (int q = 0; q < 16; ++q) acc[q] = 0.f;
  const f16* __restrict__ xcol = xf + lane * 4;

  for (int base = beg; base < end; base += 64) {
    int i = base + lane;
    int s = 0;
    float4 a4 = make_float4(0.f, 0.f, 0.f, 0.f);
    if (i < end) {
      s = csr[i];
      const float4 as4 = *(const float4*)&aS[(size_t)s * 4];
      float x0 = as4.x + ad4.x; x0 = (x0 > 0.f) ? x0 : 0.2f * x0; a4.x = __expf(x0);
      float x1 = as4.y + ad4.y; x1 = (x1 > 0.f) ? x1 : 0.2f * x1; a4.y = __expf(x1);
      float x2 = as4.z + ad4.z; x2 = (x2 > 0.f) ? x2 : 0.2f * x2; a4.z = __expf(x2);
      float x3 = as4.w + ad4.w; x3 = (x3 > 0.f) ? x3 : 0.2f * x3; a4.w = __expf(x3);
    }
    den4[0] += a4.x; den4[1] += a4.y; den4[2] += a4.z; den4[3] += a4.w;
    lsrc[wv][lane] = s;
    lal[wv][lane] = a4;
    asm volatile("s_waitcnt lgkmcnt(0)" ::: "memory");
    const int m = min(64, end - base);
    const int jm = (m + 7) & ~7;  // pad slots: alpha=0, src=0
    for (int j = 0; j < jm; j += 8) {
      int sj[8];
      f16x4 v[8];
#pragma unroll
      for (int k = 0; k < 8; ++k) sj[k] = lsrc[wv][j + k];
#pragma unroll
      for (int k = 0; k < 8; ++k) v[k] = *(const f16x4*)&xcol[(size_t)sj[k] * 256];
#pragma unroll
      for (int k = 0; k < 8; ++k) {
        const float4 a4k = lal[wv][j + k];
        const float vv[4] = {(float)v[k][0], (float)v[k][1], (float)v[k][2], (float)v[k][3]};
#pragma unroll
        for (int c = 0; c < 4; ++c) {
          acc[0 + c]  = fmaf(a4k.x, vv[c], acc[0 + c]);
          acc[4 + c]  = fmaf(a4k.y, vv[c], acc[4 + c]);
          acc[8 + c]  = fmaf(a4k.z, vv[c], acc[8 + c]);
          acc[12 + c] = fmaf(a4k.w, vv[c], acc[12 + c]);
        }
      }
    }
  }
#pragma unroll
  for (int off = 32; off; off >>= 1) {
#pragma unroll
    for (int k = 0; k < 4; ++k) den4[k] += __shfl_xor(den4[k], off);
  }
  const float inv[4] = {1.f / den4[0], 1.f / den4[1], 1.f / den4[2], 1.f / den4[3]};
#pragma unroll
  for (int h = 0; h < 4; ++h) {
    f16x4 o = {(f16)(acc[h * 4 + 0] * inv[h]), (f16)(acc[h * 4 + 1] * inv[h]),
               (f16)(acc[h * 4 + 2] * inv[h]), (f16)(acc[h * 4 + 3] * inv[h])};
    *(f16x4*)&aggX[(size_t)dst * 1024 + h * 256 + lane * 4] = o;
  }
}

// ---------------- GEMM1 per head: A2 = elu(aggX_h @ W1_h^T + b1) -----------
// A row stride 1024, col offset h*256; B rows [h*128, h*128+128); K=256.
// Pad rows clamped (outputs unused). Bias+ELU fused; writes A2 directly.
__global__ __launch_bounds__(256) void gemm1_kernel(
    const f16* __restrict__ A, const f16* __restrict__ Bm,
    const float* __restrict__ bias, f16* __restrict__ C, int Nrows) {
  __shared__ f16 lA[128 * 32];
  __shared__ f16 lB[128 * 32];
  const int h = blockIdx.x;
  const int tid = threadIdx.x;
  const int w = tid >> 6, lane = tid & 63;
  const int wm = w >> 1, wn = w & 1;
  const int rowBase = blockIdx.y * 128;
  const int lrow = lane & 15, lk = lane >> 4;
  f32x4 acc[4][4];
#pragma unroll
  for (int i = 0; i < 4; ++i)
#pragma unroll
    for (int j = 0; j < 4; ++j) acc[i][j] = (f32x4){0.f, 0.f, 0.f, 0.f};

  for (int kv = 0; kv < 256; kv += 32) {
    f16x8 stA[2], stB[2];
#pragma unroll
    for (int s = 0; s < 2; ++s) {
      int q = s * 256 + tid;
      int r = q >> 2;
      int cs = (q & 3) ^ ((r >> 1) & 3);
      int row = rowBase + r;
      if (row >= Nrows) row = Nrows - 1;  // clamp: pad outputs unused
      stA[s] = *(const f16x8*)(A + (size_t)row * 1024 + h * 256 + kv + cs * 8);
    }
#pragma unroll
    for (int s = 0; s < 2; ++s) {
      int q = s * 256 + tid;
      int r = q >> 2;
      int cs = (q & 3) ^ ((r >> 1) & 3);
      stB[s] = *(const f16x8*)(Bm + (size_t)(h * 128 + r) * 256 + kv + cs * 8);
    }
#pragma unroll
    for (int s = 0; s < 2; ++s) *(f16x8*)&lA[(size_t)(s * 256 + tid) * 8] = stA[s];
#pragma unroll
    for (int s = 0; s < 2; ++s) *(f16x8*)&lB[(size_t)(s * 256 + tid) * 8] = stB[s];
    __syncthreads();
    f16x8 aF[4], bF[4];
#pragma unroll
    for (int i = 0; i < 4; ++i) {
      int ra = wm * 64 + i * 16 + lrow;
      aF[i] = *(const f16x8*)&lA[(ra * 4 + (lk ^ ((ra >> 1) & 3))) * 8];
      int rb = wn * 64 + i * 16 + lrow;
      bF[i] = *(const f16x8*)&lB[(rb * 4 + (lk ^ ((rb >> 1) & 3))) * 8];
    }
#pragma unroll
    for (int i = 0; i < 4; ++i)
#pragma unroll
      for (int j = 0; j < 4; ++j)
        acc[i][j] = __builtin_amdgcn_mfma_f32_16x16x32_f16(aF[i], bF[j], acc[i][j], 0, 0, 0);
    __syncthreads();
  }
  // epilogue: bias + ELU, store f16 (C/D layout: col=lane&15, row=(lane>>4)*4+reg)
  float bj[4];
#pragma unroll
  for (int j = 0; j < 4; ++j) bj[j] = bias[h * 128 + wn * 64 + j * 16 + lrow];
#pragma unroll
  for (int i = 0; i < 4; ++i) {
    int row0 = rowBase + wm * 64 + i * 16 + lk * 4;
#pragma unroll
    for (int j = 0; j < 4; ++j) {
      int col = h * 128 + wn * 64 + j * 16 + lrow;
#pragma unroll
      for (int rr = 0; rr < 4; ++rr) {
        float vv = acc[i][j][rr] + bj[j];
        vv = (vv > 0.f) ? vv : (__expf(vv) - 1.f);
        C[(size_t)(row0 + rr) * 512 + col] = (f16)vv;
      }
    }
  }
}

// ------------------- GEMM2 (BM=64, TPB=128) + fused attn2 ------------------
// C[M,128] = A2 * W2^T; block covers the full 128-col row -> aS2/aD2 fused.
__global__ __launch_bounds__(128) void gemm2_kernel(
    const f16* __restrict__ A, const f16* __restrict__ Bm, f16* __restrict__ C,
    const float* __restrict__ attS, const float* __restrict__ attD,
    float* __restrict__ aS, float* __restrict__ aD,
    int K, int Ncols, int Nrows) {
  __shared__ f16 lA[64 * 32];
  __shared__ f16 lB[128 * 32];
  const int tid = threadIdx.x;
  const int w = tid >> 6, lane = tid & 63;
  const int wn = w & 1;  // wm = 0
  const int rowBase = blockIdx.y * 64;
  const int lrow = lane & 15, lk = lane >> 4;
  f32x4 acc[4][4];
#pragma unroll
  for (int i = 0; i < 4; ++i)
#pragma unroll
    for (int j = 0; j < 4; ++j) acc[i][j] = (f32x4){0.f, 0.f, 0.f, 0.f};

  for (int kv = 0; kv < K; kv += 32) {
    f16x8 stA[2], stB[4];
#pragma unroll
    for (int s = 0; s < 2; ++s) {
      int q = s * 128 + tid;
      int r = q >> 2;
      int cs = (q & 3) ^ ((r >> 1) & 3);
      stA[s] = *(const f16x8*)(A + (size_t)(rowBase + r) * K + kv + cs * 8);
    }
#pragma unroll
    for (int s = 0; s < 4; ++s) {
      int q = s * 128 + tid;
      int r = q >> 2;
      int cs = (q & 3) ^ ((r >> 1) & 3);
      stB[s] = *(const f16x8*)(Bm + (size_t)r * K + kv + cs * 8);
    }
#pragma unroll
    for (int s = 0; s < 2; ++s) *(f16x8*)&lA[(size_t)(s * 128 + tid) * 8] = stA[s];
#pragma unroll
    for (int s = 0; s < 4; ++s) *(f16x8*)&lB[(size_t)(s * 128 + tid) * 8] = stB[s];
    __syncthreads();
    f16x8 aF[4], bF[4];
#pragma unroll
    for (int i = 0; i < 4; ++i) {
      int ra = i * 16 + lrow;
      aF[i] = *(const f16x8*)&lA[(ra * 4 + (lk ^ ((ra >> 1) & 3))) * 8];
      int rb = wn * 64 + i * 16 + lrow;
      bF[i] = *(const f16x8*)&lB[(rb * 4 + (lk ^ ((rb >> 1) & 3))) * 8];
    }
#pragma unroll
    for (int i = 0; i < 4; ++i)
#pragma unroll
      for (int j = 0; j < 4; ++j)
        acc[i][j] = __builtin_amdgcn_mfma_f32_16x16x32_f16(aF[i], bF[j], acc[i][j], 0, 0, 0);
    __syncthreads();
  }
#pragma unroll
  for (int i = 0; i < 4; ++i) {
    int row0 = rowBase + i * 16 + lk * 4;
#pragma unroll
    for (int j = 0; j < 4; ++j) {
      int col = wn * 64 + j * 16 + lrow;
#pragma unroll
      for (int rr = 0; rr < 4; ++rr)
        C[(size_t)(row0 + rr) * Ncols + col] = (f16)acc[i][j][rr];
    }
  }
  // Fused attn2 epilogue (H = 1)
  float sv[4], dv[4];
#pragma unroll
  for (int j = 0; j < 4; ++j) {
    int cl = wn * 64 + j * 16 + lrow;
    sv[j] = attS[cl];
    dv[j] = attD[cl];
  }
  float* sred = (float*)lA;  // [wn][64][2] = 1 KB
#pragma unroll
  for (int i = 0; i < 4; ++i) {
#pragma unroll
    for (int rr = 0; rr < 4; ++rr) {
      float ps = 0.f, pd = 0.f;
#pragma unroll
      for (int j = 0; j < 4; ++j) {
        ps = fmaf(acc[i][j][rr], sv[j], ps);
        pd = fmaf(acc[i][j][rr], dv[j], pd);
      }
#pragma unroll
      for (int off = 1; off < 16; off <<= 1) {
        ps += __shfl_xor(ps, off);
        pd += __shfl_xor(pd, off);
      }
      if (lrow == 0) {
        int rloc = i * 16 + lk * 4 + rr;
        sred[(wn * 64 + rloc) * 2 + 0] = ps;
        sred[(wn * 64 + rloc) * 2 + 1] = pd;
      }
    }
  }
  __syncthreads();
  if (tid < 64) {
    int row = rowBase + tid;
    if (row < Nrows) {
      aS[row] = sred[tid * 2] + sred[(64 + tid) * 2];
      aD[row] = sred[tid * 2 + 1] + sred[(64 + tid) * 2 + 1];
    }
  }
}

// ------------- layer-2 aggregation + ELU + fused classifier ----------------
// One wave per dst (C=128): 2 edges/iter (half=lane>>5, 32 lanes x f16x4),
// alpha fused into staging; branch-free 8-pair unroll via alpha=0 pads.
__global__ __launch_bounds__(256) void agg2_kernel(
    const int* __restrict__ row_ptr, const int* __restrict__ csr,
    const float* __restrict__ aS, const float* __restrict__ aD,
    const f16* __restrict__ xw2, const float* __restrict__ b2,
    const float* __restrict__ Wc, const float* __restrict__ bc,
    float* __restrict__ out, int n) {
  __shared__ float2 led[4][64];
  const int wv = threadIdx.x >> 6, lane = threadIdx.x & 63;
  const int dst = blockIdx.x * 4 + wv;
  if (dst >= n) return;
  const int beg = row_ptr[dst], end = row_ptr[dst + 1];
  const int half = lane >> 5, lc = lane & 31;
  const float ad = aD[dst];
  float den = 0.f;
  float acc[4] = {0.f, 0.f, 0.f, 0.f};
  const f16* __restrict__ xrow = xw2 + lc * 4;

  for (int base = beg; base < end; base += 64) {
    int i = base + lane;
    float2 pa = make_float2(__int_as_float(0), 0.f);
    if (i < end) {
      int s = csr[i];
      float x = aS[s] + ad;
      x = (x > 0.f) ? x : 0.2f * x;
      pa = make_float2(__int_as_float(s), __expf(x));
    }
    den += pa.y;
    led[wv][lane] = pa;
    asm volatile("s_waitcnt lgkmcnt(0)" ::: "memory");
    const int m = min(64, end - base);
    const int pr = (((m + 1) >> 1) + 7) & ~7;  // pad pairs: alpha=0, src=0
    for (int p = 0; p < pr; p += 8) {
      int sj[8];
      float aj[8];
      f16x4 v[8];
#pragma unroll
      for (int k = 0; k < 8; ++k) {
        float2 q = led[wv][(p + k) * 2 + half];
        sj[k] = __float_as_int(q.x);
        aj[k] = q.y;
      }
#pragma unroll
      for (int k = 0; k < 8; ++k) v[k] = *(const f16x4*)&xrow[(size_t)sj[k] * 128];
#pragma unroll
      for (int k = 0; k < 8; ++k) {
        acc[0] = fmaf(aj[k], (float)v[k][0], acc[0]);
        acc[1] = fmaf(aj[k], (float)v[k][1], acc[1]);
        acc[2] = fmaf(aj[k], (float)v[k][2], acc[2]);
        acc[3] = fmaf(aj[k], (float)v[k][3], acc[3]);
      }
    }
  }
#pragma unroll
  for (int off = 32; off; off >>= 1) den += __shfl_xor(den, off);
  const float inv = 1.f / den;
#pragma unroll
  for (int k = 0; k < 4; ++k) acc[k] += __shfl_xor(acc[k], 32);
  const int c = lc * 4;
  const float4 bb = *(const float4*)&b2[c];
  const float4 w0 = *(const float4*)&Wc[c];
  const float4 w1 = *(const float4*)&Wc[128 + c];
  const float bv[4] = {bb.x, bb.y, bb.z, bb.w};
  const float w0v[4] = {w0.x, w0.y, w0.z, w0.w};
  const float w1v[4] = {w1.x, w1.y, w1.z, w1.w};
  float l0 = 0.f, l1 = 0.f;
#pragma unroll
  for (int k = 0; k < 4; ++k) {
    float vv = acc[k] * inv + bv[k];
    vv = (vv > 0.f) ? vv : (__expf(vv) - 1.f);
    l0 = fmaf(vv, w0v[k], l0);
    l1 = fmaf(vv, w1v[k], l1);
  }
#pragma unroll
  for (int off = 16; off; off >>= 1) {
    l0 += __shfl_xor(l0, off);
    l1 += __shfl_xor(l1, off);
  }
  if (lane == 0) {
    out[dst * 2] = l0 + bc[0];
    out[dst * 2 + 1] = l1 + bc[1];
  }
}

// ---------------------------------------------------------------------------

extern "C" void kernel_launch(void* const* d_in, const int* in_sizes, int n_in,
                              void* d_out, int out_size, void* d_ws, size_t ws_size,
                              hipStream_t stream) {
  const float* x     = (const float*)d_in[0];
  const int*   ei    = (const int*)d_in[1];
  const float* W1    = (const float*)d_in[2];
  const float* att1s = (const float*)d_in[3];
  const float* att1d = (const float*)d_in[4];
  const float* b1    = (const float*)d_in[5];
  const float* W2    = (const float*)d_in[6];
  const float* att2s = (const float*)d_in[7];
  const float* att2d = (const float*)d_in[8];
  const float* b2    = (const float*)d_in[9];
  const float* Wc    = (const float*)d_in[10];
  const float* bc    = (const float*)d_in[11];
  float* out = (float*)d_out;

  const int N = in_sizes[0] / 256;
  const int E = in_sizes[1] / 2;
  const int EA = E + N;
  const int Mpad = (N + 127) & ~127;
  const int NB = (N + 255) / 256;
  const int EB = (EA + 255) / 256;

  char* base = (char*)d_ws;
  size_t off = 0;
  auto alloc = [&](size_t bytes) -> char* {
    char* p = base + off;
    off = (off + bytes + 255) & ~(size_t)255;
    return p;
  };
  f16* aggX = (f16*)alloc((size_t)Mpad * 1024 * sizeof(f16));  // x-space agg (4 heads)
  f16* xf   = (f16*)alloc((size_t)Mpad * 256 * sizeof(f16));   // x in f16
  f16* B1f  = (f16*)alloc((size_t)512 * 256 * sizeof(f16));    // W1 f16
  f16* A2   = (f16*)alloc((size_t)Mpad * 512 * sizeof(f16));   // h = elu(layer1)
  f16* B2f  = (f16*)alloc((size_t)128 * 512 * sizeof(f16));    // W2 f16
  f16* xw2h = (f16*)alloc((size_t)Mpad * 128 * sizeof(f16));   // layer2 pre-agg
  float* attW = (float*)alloc((size_t)256 * 8 * sizeof(float));
  float* aS1 = (float*)alloc((size_t)N * 4 * sizeof(float));
  float* aD1 = (float*)alloc((size_t)N * 4 * sizeof(float));
  float* aS2 = (float*)alloc((size_t)N * sizeof(float));
  float* aD2 = (float*)alloc((size_t)N * sizeof(float));
  int* deg     = (int*)alloc((size_t)N * sizeof(int));
  int* row_ptr = (int*)alloc((size_t)(N + 1) * sizeof(int));
  int* cursor  = (int*)alloc((size_t)N * sizeof(int));
  int* csr     = (int*)alloc((size_t)EA * sizeof(int));
  int* tmp     = (int*)alloc((size_t)N * sizeof(int));
  int* bsum    = (int*)alloc((size_t)NB * sizeof(int));
  int* boff    = (int*)alloc((size_t)NB * sizeof(int));
  int* flag    = (int*)alloc(256);
  (void)n_in; (void)out_size; (void)ws_size;

  hipMemsetAsync(deg, 0, (size_t)N * sizeof(int), stream);
  if (Mpad > N)  // zero A2 pad rows so GEMM2 pad outputs stay finite
    hipMemsetAsync(A2 + (size_t)N * 512, 0, (size_t)(Mpad - N) * 512 * sizeof(f16), stream);

  detect_i64_kernel<<<1, 64, 0, stream>>>(ei, flag);
  hist_kernel<<<EB, 256, 0, stream>>>(ei, E, N, flag, deg);
  scan1_kernel<<<NB, 256, 0, stream>>>(deg, tmp, bsum, N);
  scan2_kernel<<<1, 256, 0, stream>>>(bsum, boff, NB);
  scan3_kernel<<<NB, 256, 0, stream>>>(deg, tmp, boff, row_ptr, cursor, N);
  scatter_kernel<<<EB, 256, 0, stream>>>(ei, E, N, flag, cursor, csr);

  attw_kernel<<<4, 256, 0, stream>>>(W1, att1s, att1d, attW);
  cvtx_kernel<<<(N + 3) / 4, 256, 0, stream>>>(x, attW, xf, aS1, aD1, N);
  cvt_f16_kernel<<<(512 * 64 + 255) / 256, 256, 0, stream>>>(W1, B1f, 512, 512, 256, 6);
  cvt_f16_kernel<<<(128 * 128 + 255) / 256, 256, 0, stream>>>(W2, B2f, 128, 128, 512, 7);

  agg1_kernel<<<(N + 3) / 4, 256, 0, stream>>>(row_ptr, csr, aS1, aD1, xf, aggX, N);
  dim3 g1(4, Mpad / 128);
  gemm1_kernel<<<g1, 256, 0, stream>>>(aggX, B1f, b1, A2, N);

  dim3 g2(1, Mpad / 64);
  gemm2_kernel<<<g2, 128, 0, stream>>>(A2, B2f, xw2h, att2s, att2d, aS2, aD2, 512, 128, N);
  agg2_kernel<<<(N + 3) / 4, 256, 0, stream>>>(row_ptr, csr, aS2, aD2, xw2h, b2, Wc, bc, out, N);
}

// Round 10
// 393.837 us; speedup vs baseline: 1.9330x; 1.0924x over previous
//
#include <hip/hip_runtime.h>
#include <stdint.h>

// ---------------------------------------------------------------------------
// GAT bot detector, 2-layer, N=50000 E=800000 IN=256 HID=128 HEADS=4.
// Round 10: r9 pipeline (x-space agg1) + three structural fixes:
//  - cvtx: rank-1 attn weights in per-lane REGISTERS (attW transposed),
//    killing a 32-way LDS bank conflict x32 reads per row.
//  - gemm2: 4-wave blocks (wave-tile 32x64), 12 waves/CU (was 6).
//  - detect_i64: one wave + ballot (was 256 serial loads on 1 thread).
// Sync-staged GEMMs kept (global_load_lds proved racy in r2); static wave->
// dst maps (r8 single-counter queue serialized on cross-XCD atomics).
// ---------------------------------------------------------------------------

typedef _Float16 f16;
typedef f16 f16x8 __attribute__((ext_vector_type(8)));
typedef f16 f16x4 __attribute__((ext_vector_type(4)));
typedef f16 f16x2 __attribute__((ext_vector_type(2)));
typedef float f32x4 __attribute__((ext_vector_type(4)));

// --------------------------- CSR construction ------------------------------

__global__ void detect_i64_kernel(const int* __restrict__ ei, int* __restrict__ flag) {
  const int lane = threadIdx.x & 63;
  int nz = 0;
#pragma unroll
  for (int w = 0; w < 4; ++w) nz |= ei[2 * (lane * 4 + w) + 1];
  unsigned long long b = __ballot(nz != 0);
  if (lane == 0) *flag = (b == 0ull) ? 1 : 0;
}

__global__ void hist_kernel(const int* __restrict__ ei, int E, int N,
                            const int* __restrict__ flagp, int* __restrict__ deg) {
  int idx = blockIdx.x * blockDim.x + threadIdx.x;
  int EA = E + N;
  if (idx >= EA) return;
  int dst;
  if (idx < E) {
    dst = (*flagp) ? ei[2 * ((size_t)E + idx)] : ei[(size_t)E + idx];
  } else {
    dst = idx - E;  // self loop
  }
  if ((unsigned)dst >= (unsigned)N) return;
  atomicAdd(&deg[dst], 1);
}

// 3-phase scan: per-block inclusive -> block-sums scan -> fixup.
__global__ __launch_bounds__(256) void scan1_kernel(const int* __restrict__ deg,
                                                    int* __restrict__ tmp,
                                                    int* __restrict__ bsum, int n) {
  __shared__ int sd[256];
  const int t = threadIdx.x;
  const int i = blockIdx.x * 256 + t;
  int x = (i < n) ? deg[i] : 0;
  sd[t] = x;
  __syncthreads();
  for (int off = 1; off < 256; off <<= 1) {
    int v = (t >= off) ? sd[t - off] : 0;
    __syncthreads();
    sd[t] += v;
    __syncthreads();
  }
  if (i < n) tmp[i] = sd[t];
  if (t == 255) bsum[blockIdx.x] = sd[255];
}

__global__ __launch_bounds__(256) void scan2_kernel(const int* __restrict__ bsum,
                                                    int* __restrict__ boff, int nb) {
  __shared__ int sd[256];
  const int t = threadIdx.x;
  int x = (t < nb) ? bsum[t] : 0;
  sd[t] = x;
  __syncthreads();
  for (int off = 1; off < 256; off <<= 1) {
    int v = (t >= off) ? sd[t - off] : 0;
    __syncthreads();
    sd[t] += v;
    __syncthreads();
  }
  if (t < nb) boff[t] = sd[t] - x;  // exclusive
}

__global__ void scan3_kernel(const int* __restrict__ deg, const int* __restrict__ tmp,
                             const int* __restrict__ boff, int* __restrict__ row_ptr,
                             int* __restrict__ cursor, int n) {
  int i = blockIdx.x * 256 + threadIdx.x;
  if (i >= n) return;
  int g = tmp[i] + boff[i >> 8];
  row_ptr[i + 1] = g;
  cursor[i] = g - deg[i];
  if (i == 0) row_ptr[0] = 0;
}

__global__ void scatter_kernel(const int* __restrict__ ei, int E, int N,
                               const int* __restrict__ flagp,
                               int* __restrict__ cursor, int* __restrict__ csr) {
  int idx = blockIdx.x * blockDim.x + threadIdx.x;
  int EA = E + N;
  if (idx >= EA) return;
  int src, dst;
  if (idx < E) {
    if (*flagp) { src = ei[2 * (size_t)idx]; dst = ei[2 * ((size_t)E + idx)]; }
    else        { src = ei[(size_t)idx];     dst = ei[(size_t)E + idx]; }
  } else {
    src = dst = idx - E;
  }
  if ((unsigned)dst >= (unsigned)N || (unsigned)src >= (unsigned)N) return;
  int pos = atomicAdd(&cursor[dst], 1);
  csr[pos] = src;
}

// --------------------------- f32 -> f16 convert ----------------------------
__global__ void cvt_f16_kernel(const float* __restrict__ src, f16* __restrict__ dst,
                               int srcRows, int dstRows, int cols, int gshift) {
  int idx = blockIdx.x * blockDim.x + threadIdx.x;
  int total = dstRows << gshift;
  if (idx >= total) return;
  int row = idx >> gshift;
  int col = (idx & ((1 << gshift) - 1)) * 4;
  float4 v = make_float4(0.f, 0.f, 0.f, 0.f);
  if (row < srcRows) v = *(const float4*)&src[(size_t)row * cols + col];
  f16x4 o = {(f16)v.x, (f16)v.y, (f16)v.z, (f16)v.w};
  *(f16x4*)&dst[(size_t)row * cols + col] = o;
}

// --------------- rank-1 attention projection: attWT[8][256] ----------------
// attWT[(h*2+0)*256 + c] = sum_k W1[h*128+k, c] * att1s[h,k]; +1 -> att1d.
__global__ void attw_kernel(const float* __restrict__ W1, const float* __restrict__ s1,
                            const float* __restrict__ d1, float* __restrict__ attWT) {
  const int h = blockIdx.x;
  const int c = threadIdx.x;
  float ps = 0.f, pd = 0.f;
  for (int k = 0; k < 128; ++k) {
    float w = W1[(size_t)(h * 128 + k) * 256 + c];
    ps = fmaf(w, s1[h * 128 + k], ps);
    pd = fmaf(w, d1[h * 128 + k], pd);
  }
  attWT[(h * 2 + 0) * 256 + c] = ps;
  attWT[(h * 2 + 1) * 256 + c] = pd;
}

// --------- fused x->f16 convert + per-node attn coefs (aSD1) ---------------
// Weights live in per-lane registers (each lane only ever needs cols
// lane*4..lane*4+3 of attWT) -> no LDS, no bank conflicts. 4 rows per wave.
__global__ __launch_bounds__(256) void cvtx_kernel(
    const float* __restrict__ x, const float* __restrict__ attWT,
    f16* __restrict__ xf, float* __restrict__ aS, float* __restrict__ aD, int n) {
  const int wv = threadIdx.x >> 6, lane = threadIdx.x & 63;
  float4 wr[8];
#pragma unroll
  for (int j = 0; j < 8; ++j) wr[j] = *(const float4*)&attWT[j * 256 + lane * 4];
  const int row0 = (blockIdx.x * 4 + wv) * 4;
#pragma unroll
  for (int r = 0; r < 4; ++r) {
    const int row = row0 + r;
    if (row >= n) return;
    const float4 v = *(const float4*)&x[(size_t)row * 256 + lane * 4];
    f16x4 o = {(f16)v.x, (f16)v.y, (f16)v.z, (f16)v.w};
    *(f16x4*)&xf[(size_t)row * 256 + lane * 4] = o;
    float p[8];
#pragma unroll
    for (int j = 0; j < 8; ++j)
      p[j] = v.x * wr[j].x + v.y * wr[j].y + v.z * wr[j].z + v.w * wr[j].w;
#pragma unroll
    for (int off = 32; off; off >>= 1)
#pragma unroll
      for (int j = 0; j < 8; ++j) p[j] += __shfl_xor(p[j], off);
    if (lane == 0) {
#pragma unroll
      for (int h = 0; h < 4; ++h) {
        aS[(size_t)row * 4 + h] = p[h * 2];
        aD[(size_t)row * 4 + h] = p[h * 2 + 1];
      }
    }
  }
}

// ------------------- layer-1 x-space aggregation (per dst) -----------------
// One wave per dst (static map). Staging per 64 edges: csr + aS1 gather ->
// alpha4 in-register -> wave-private LDS. Main loop: branch-free 8-deep
// unroll; lane owns 4 x-cols (f16x4 8B gather); 16 fma (4 heads x 4 cols).
// Epilogue: normalize per head, write aggX[dst, h*256 + cols] f16.
__global__ __launch_bounds__(256) void agg1_kernel(
    const int* __restrict__ row_ptr, const int* __restrict__ csr,
    const float* __restrict__ aS, const float* __restrict__ aD,
    const f16* __restrict__ xf, f16* __restrict__ aggX, int n) {
  __shared__ float4 lal[4][64];
  __shared__ int lsrc[4][64];
  const int wv = threadIdx.x >> 6, lane = threadIdx.x & 63;
  const int dst = blockIdx.x * 4 + wv;
  if (dst >= n) return;
  const int beg = row_ptr[dst], end = row_ptr[dst + 1];
  const float4 ad4 = *(const float4*)&aD[(size_t)dst * 4];
  f32x4 den4 = {0.f, 0.f, 0.f, 0.f};
  float acc[16];
#pragma unroll
  for (int q = 0; q < 16; ++q) acc[q] = 0.f;
  const f16* __restrict__ xcol = xf + lane * 4;

  for (int base = beg; base < end; base += 64) {
    int i = base + lane;
    int s = 0;
    float4 a4 = make_float4(0.f, 0.f, 0.f, 0.f);
    if (i < end) {
      s = csr[i];
      const float4 as4 = *(const float4*)&aS[(size_t)s * 4];
      float x0 = as4.x + ad4.x; x0 = (x0 > 0.f) ? x0 : 0.2f * x0; a4.x = __expf(x0);
      float x1 = as4.y + ad4.y; x1 = (x1 > 0.f) ? x1 : 0.2f * x1; a4.y = __expf(x1);
      float x2 = as4.z + ad4.z; x2 = (x2 > 0.f) ? x2 : 0.2f * x2; a4.z = __expf(x2);
      float x3 = as4.w + ad4.w; x3 = (x3 > 0.f) ? x3 : 0.2f * x3; a4.w = __expf(x3);
    }
    den4[0] += a4.x; den4[1] += a4.y; den4[2] += a4.z; den4[3] += a4.w;
    lsrc[wv][lane] = s;
    lal[wv][lane] = a4;
    asm volatile("s_waitcnt lgkmcnt(0)" ::: "memory");
    const int m = min(64, end - base);
    const int jm = (m + 7) & ~7;  // pad slots: alpha=0, src=0
    for (int j = 0; j < jm; j += 8) {
      int sj[8];
      f16x4 v[8];
#pragma unroll
      for (int k = 0; k < 8; ++k) sj[k] = lsrc[wv][j + k];
#pragma unroll
      for (int k = 0; k < 8; ++k) v[k] = *(const f16x4*)&xcol[(size_t)sj[k] * 256];
#pragma unroll
      for (int k = 0; k < 8; ++k) {
        const float4 a4k = lal[wv][j + k];
        const float vv[4] = {(float)v[k][0], (float)v[k][1], (float)v[k][2], (float)v[k][3]};
#pragma unroll
        for (int c = 0; c < 4; ++c) {
          acc[0 + c]  = fmaf(a4k.x, vv[c], acc[0 + c]);
          acc[4 + c]  = fmaf(a4k.y, vv[c], acc[4 + c]);
          acc[8 + c]  = fmaf(a4k.z, vv[c], acc[8 + c]);
          acc[12 + c] = fmaf(a4k.w, vv[c], acc[12 + c]);
        }
      }
    }
  }
#pragma unroll
  for (int off = 32; off; off >>= 1) {
#pragma unroll
    for (int k = 0; k < 4; ++k) den4[k] += __shfl_xor(den4[k], off);
  }
  const float inv[4] = {1.f / den4[0], 1.f / den4[1], 1.f / den4[2], 1.f / den4[3]};
#pragma unroll
  for (int h = 0; h < 4; ++h) {
    f16x4 o = {(f16)(acc[h * 4 + 0] * inv[h]), (f16)(acc[h * 4 + 1] * inv[h]),
               (f16)(acc[h * 4 + 2] * inv[h]), (f16)(acc[h * 4 + 3] * inv[h])};
    *(f16x4*)&aggX[(size_t)dst * 1024 + h * 256 + lane * 4] = o;
  }
}

// ---------------- GEMM1 per head: A2 = elu(aggX_h @ W1_h^T + b1) -----------
// A row stride 1024, col offset h*256; B rows [h*128, h*128+128); K=256.
// Pad rows clamped (outputs unused). Bias+ELU fused; writes A2 directly.
__global__ __launch_bounds__(256) void gemm1_kernel(
    const f16* __restrict__ A, const f16* __restrict__ Bm,
    const float* __restrict__ bias, f16* __restrict__ C, int Nrows) {
  __shared__ f16 lA[128 * 32];
  __shared__ f16 lB[128 * 32];
  const int h = blockIdx.x;
  const int tid = threadIdx.x;
  const int w = tid >> 6, lane = tid & 63;
  const int wm = w >> 1, wn = w & 1;
  const int rowBase = blockIdx.y * 128;
  const int lrow = lane & 15, lk = lane >> 4;
  f32x4 acc[4][4];
#pragma unroll
  for (int i = 0; i < 4; ++i)
#pragma unroll
    for (int j = 0; j < 4; ++j) acc[i][j] = (f32x4){0.f, 0.f, 0.f, 0.f};

  for (int kv = 0; kv < 256; kv += 32) {
    f16x8 stA[2], stB[2];
#pragma unroll
    for (int s = 0; s < 2; ++s) {
      int q = s * 256 + tid;
      int r = q >> 2;
      int cs = (q & 3) ^ ((r >> 1) & 3);
      int row = rowBase + r;
      if (row >= Nrows) row = Nrows - 1;  // clamp: pad outputs unused
      stA[s] = *(const f16x8*)(A + (size_t)row * 1024 + h * 256 + kv + cs * 8);
    }
#pragma unroll
    for (int s = 0; s < 2; ++s) {
      int q = s * 256 + tid;
      int r = q >> 2;
      int cs = (q & 3) ^ ((r >> 1) & 3);
      stB[s] = *(const f16x8*)(Bm + (size_t)(h * 128 + r) * 256 + kv + cs * 8);
    }
#pragma unroll
    for (int s = 0; s < 2; ++s) *(f16x8*)&lA[(size_t)(s * 256 + tid) * 8] = stA[s];
#pragma unroll
    for (int s = 0; s < 2; ++s) *(f16x8*)&lB[(size_t)(s * 256 + tid) * 8] = stB[s];
    __syncthreads();
    f16x8 aF[4], bF[4];
#pragma unroll
    for (int i = 0; i < 4; ++i) {
      int ra = wm * 64 + i * 16 + lrow;
      aF[i] = *(const f16x8*)&lA[(ra * 4 + (lk ^ ((ra >> 1) & 3))) * 8];
      int rb = wn * 64 + i * 16 + lrow;
      bF[i] = *(const f16x8*)&lB[(rb * 4 + (lk ^ ((rb >> 1) & 3))) * 8];
    }
#pragma unroll
    for (int i = 0; i < 4; ++i)
#pragma unroll
      for (int j = 0; j < 4; ++j)
        acc[i][j] = __builtin_amdgcn_mfma_f32_16x16x32_f16(aF[i], bF[j], acc[i][j], 0, 0, 0);
    __syncthreads();
  }
  // epilogue: bias + ELU, store f16 (C/D layout: col=lane&15, row=(lane>>4)*4+reg)
  float bj[4];
#pragma unroll
  for (int j = 0; j < 4; ++j) bj[j] = bias[h * 128 + wn * 64 + j * 16 + lrow];
#pragma unroll
  for (int i = 0; i < 4; ++i) {
    int row0 = rowBase + wm * 64 + i * 16 + lk * 4;
#pragma unroll
    for (int j = 0; j < 4; ++j) {
      int col = h * 128 + wn * 64 + j * 16 + lrow;
#pragma unroll
      for (int rr = 0; rr < 4; ++rr) {
        float vv = acc[i][j][rr] + bj[j];
        vv = (vv > 0.f) ? vv : (__expf(vv) - 1.f);
        C[(size_t)(row0 + rr) * 512 + col] = (f16)vv;
      }
    }
  }
}

// ------------- GEMM2 (BM=64, TPB=256, wave-tile 32x64) + fused attn2 -------
// C[M,128] = A2 * W2^T; 4 waves: wm=w>>1 row-half (32), wn=w&1 col-half (64).
// 784 blocks x 4 waves -> ~12 waves/CU (r9's 2-wave version had ~6).
__global__ __launch_bounds__(256) void gemm2_kernel(
    const f16* __restrict__ A, const f16* __restrict__ Bm, f16* __restrict__ C,
    const float* __restrict__ attS, const float* __restrict__ attD,
    float* __restrict__ aS, float* __restrict__ aD,
    int K, int Ncols, int Nrows) {
  __shared__ f16 lA[64 * 32];
  __shared__ f16 lB[128 * 32];
  const int tid = threadIdx.x;
  const int w = tid >> 6, lane = tid & 63;
  const int wm = w >> 1, wn = w & 1;
  const int rowBase = blockIdx.y * 64;
  const int lrow = lane & 15, lk = lane >> 4;
  f32x4 acc[2][4];
#pragma unroll
  for (int i = 0; i < 2; ++i)
#pragma unroll
    for (int j = 0; j < 4; ++j) acc[i][j] = (f32x4){0.f, 0.f, 0.f, 0.f};

  for (int kv = 0; kv < K; kv += 32) {
    f16x8 stA, stB[2];
    {
      int q = tid;  // 256 chunks = 64 rows x 4
      int r = q >> 2;
      int cs = (q & 3) ^ ((r >> 1) & 3);
      stA = *(const f16x8*)(A + (size_t)(rowBase + r) * K + kv + cs * 8);
    }
#pragma unroll
    for (int s = 0; s < 2; ++s) {
      int q = s * 256 + tid;
      int r = q >> 2;
      int cs = (q & 3) ^ ((r >> 1) & 3);
      stB[s] = *(const f16x8*)(Bm + (size_t)r * K + kv + cs * 8);
    }
    *(f16x8*)&lA[(size_t)tid * 8] = stA;
#pragma unroll
    for (int s = 0; s < 2; ++s) *(f16x8*)&lB[(size_t)(s * 256 + tid) * 8] = stB[s];
    __syncthreads();
    f16x8 aF[2], bF[4];
#pragma unroll
    for (int i = 0; i < 2; ++i) {
      int ra = wm * 32 + i * 16 + lrow;
      aF[i] = *(const f16x8*)&lA[(ra * 4 + (lk ^ ((ra >> 1) & 3))) * 8];
    }
#pragma unroll
    for (int j = 0; j < 4; ++j) {
      int rb = wn * 64 + j * 16 + lrow;
      bF[j] = *(const f16x8*)&lB[(rb * 4 + (lk ^ ((rb >> 1) & 3))) * 8];
    }
#pragma unroll
    for (int i = 0; i < 2; ++i)
#pragma unroll
      for (int j = 0; j < 4; ++j)
        acc[i][j] = __builtin_amdgcn_mfma_f32_16x16x32_f16(aF[i], bF[j], acc[i][j], 0, 0, 0);
    __syncthreads();
  }
#pragma unroll
  for (int i = 0; i < 2; ++i) {
    int row0 = rowBase + wm * 32 + i * 16 + lk * 4;
#pragma unroll
    for (int j = 0; j < 4; ++j) {
      int col = wn * 64 + j * 16 + lrow;
#pragma unroll
      for (int rr = 0; rr < 4; ++rr)
        C[(size_t)(row0 + rr) * Ncols + col] = (f16)acc[i][j][rr];
    }
  }
  // Fused attn2 epilogue (H=1): rows split by wm, cols by wn.
  float sv[4], dv[4];
#pragma unroll
  for (int j = 0; j < 4; ++j) {
    int cl = wn * 64 + j * 16 + lrow;
    sv[j] = attS[cl];
    dv[j] = attD[cl];
  }
  __shared__ float sred[2][2][32][2];  // [wm][wn][row][s/d]
#pragma unroll
  for (int i = 0; i < 2; ++i) {
#pragma unroll
    for (int rr = 0; rr < 4; ++rr) {
      float ps = 0.f, pd = 0.f;
#pragma unroll
      for (int j = 0; j < 4; ++j) {
        ps = fmaf(acc[i][j][rr], sv[j], ps);
        pd = fmaf(acc[i][j][rr], dv[j], pd);
      }
#pragma unroll
      for (int off = 1; off < 16; off <<= 1) {
        ps += __shfl_xor(ps, off);
        pd += __shfl_xor(pd, off);
      }
      if (lrow == 0) {
        int rloc = i * 16 + lk * 4 + rr;
        sred[wm][wn][rloc][0] = ps;
        sred[wm][wn][rloc][1] = pd;
      }
    }
  }
  __syncthreads();
  if (tid < 64) {
    int row = rowBase + tid;
    if (row < Nrows) {
      int m = tid >> 5, rl = tid & 31;
      aS[row] = sred[m][0][rl][0] + sred[m][1][rl][0];
      aD[row] = sred[m][0][rl][1] + sred[m][1][rl][1];
    }
  }
}

// ------------- layer-2 aggregation + ELU + fused classifier ----------------
// One wave per dst (C=128): 2 edges/iter (half=lane>>5, 32 lanes x f16x4),
// alpha fused into staging; branch-free 8-pair unroll via alpha=0 pads.
__global__ __launch_bounds__(256) void agg2_kernel(
    const int* __restrict__ row_ptr, const int* __restrict__ csr,
    const float* __restrict__ aS, const float* __restrict__ aD,
    const f16* __restrict__ xw2, const float* __restrict__ b2,
    const float* __restrict__ Wc, const float* __restrict__ bc,
    float* __restrict__ out, int n) {
  __shared__ float2 led[4][64];
  const int wv = threadIdx.x >> 6, lane = threadIdx.x & 63;
  const int dst = blockIdx.x * 4 + wv;
  if (dst >= n) return;
  const int beg = row_ptr[dst], end = row_ptr[dst + 1];
  const int half = lane >> 5, lc = lane & 31;
  const float ad = aD[dst];
  float den = 0.f;
  float acc[4] = {0.f, 0.f, 0.f, 0.f};
  const f16* __restrict__ xrow = xw2 + lc * 4;

  for (int base = beg; base < end; base += 64) {
    int i = base + lane;
    float2 pa = make_float2(__int_as_float(0), 0.f);
    if (i < end) {
      int s = csr[i];
      float x = aS[s] + ad;
      x = (x > 0.f) ? x : 0.2f * x;
      pa = make_float2(__int_as_float(s), __expf(x));
    }
    den += pa.y;
    led[wv][lane] = pa;
    asm volatile("s_waitcnt lgkmcnt(0)" ::: "memory");
    const int m = min(64, end - base);
    const int pr = (((m + 1) >> 1) + 7) & ~7;  // pad pairs: alpha=0, src=0
    for (int p = 0; p < pr; p += 8) {
      int sj[8];
      float aj[8];
      f16x4 v[8];
#pragma unroll
      for (int k = 0; k < 8; ++k) {
        float2 q = led[wv][(p + k) * 2 + half];
        sj[k] = __float_as_int(q.x);
        aj[k] = q.y;
      }
#pragma unroll
      for (int k = 0; k < 8; ++k) v[k] = *(const f16x4*)&xrow[(size_t)sj[k] * 128];
#pragma unroll
      for (int k = 0; k < 8; ++k) {
        acc[0] = fmaf(aj[k], (float)v[k][0], acc[0]);
        acc[1] = fmaf(aj[k], (float)v[k][1], acc[1]);
        acc[2] = fmaf(aj[k], (float)v[k][2], acc[2]);
        acc[3] = fmaf(aj[k], (float)v[k][3], acc[3]);
      }
    }
  }
#pragma unroll
  for (int off = 32; off; off >>= 1) den += __shfl_xor(den, off);
  const float inv = 1.f / den;
#pragma unroll
  for (int k = 0; k < 4; ++k) acc[k] += __shfl_xor(acc[k], 32);
  const int c = lc * 4;
  const float4 bb = *(const float4*)&b2[c];
  const float4 w0 = *(const float4*)&Wc[c];
  const float4 w1 = *(const float4*)&Wc[128 + c];
  const float bv[4] = {bb.x, bb.y, bb.z, bb.w};
  const float w0v[4] = {w0.x, w0.y, w0.z, w0.w};
  const float w1v[4] = {w1.x, w1.y, w1.z, w1.w};
  float l0 = 0.f, l1 = 0.f;
#pragma unroll
  for (int k = 0; k < 4; ++k) {
    float vv = acc[k] * inv + bv[k];
    vv = (vv > 0.f) ? vv : (__expf(vv) - 1.f);
    l0 = fmaf(vv, w0v[k], l0);
    l1 = fmaf(vv, w1v[k], l1);
  }
#pragma unroll
  for (int off = 16; off; off >>= 1) {
    l0 += __shfl_xor(l0, off);
    l1 += __shfl_xor(l1, off);
  }
  if (lane == 0) {
    out[dst * 2] = l0 + bc[0];
    out[dst * 2 + 1] = l1 + bc[1];
  }
}

// ---------------------------------------------------------------------------

extern "C" void kernel_launch(void* const* d_in, const int* in_sizes, int n_in,
                              void* d_out, int out_size, void* d_ws, size_t ws_size,
                              hipStream_t stream) {
  const float* x     = (const float*)d_in[0];
  const int*   ei    = (const int*)d_in[1];
  const float* W1    = (const float*)d_in[2];
  const float* att1s = (const float*)d_in[3];
  const float* att1d = (const float*)d_in[4];
  const float* b1    = (const float*)d_in[5];
  const float* W2    = (const float*)d_in[6];
  const float* att2s = (const float*)d_in[7];
  const float* att2d = (const float*)d_in[8];
  const float* b2    = (const float*)d_in[9];
  const float* Wc    = (const float*)d_in[10];
  const float* bc    = (const float*)d_in[11];
  float* out = (float*)d_out;

  const int N = in_sizes[0] / 256;
  const int E = in_sizes[1] / 2;
  const int EA = E + N;
  const int Mpad = (N + 127) & ~127;
  const int NB = (N + 255) / 256;
  const int EB = (EA + 255) / 256;

  char* base = (char*)d_ws;
  size_t off = 0;
  auto alloc = [&](size_t bytes) -> char* {
    char* p = base + off;
    off = (off + bytes + 255) & ~(size_t)255;
    return p;
  };
  f16* aggX = (f16*)alloc((size_t)Mpad * 1024 * sizeof(f16));  // x-space agg (4 heads)
  f16* xf   = (f16*)alloc((size_t)Mpad * 256 * sizeof(f16));   // x in f16
  f16* B1f  = (f16*)alloc((size_t)512 * 256 * sizeof(f16));    // W1 f16
  f16* A2   = (f16*)alloc((size_t)Mpad * 512 * sizeof(f16));   // h = elu(layer1)
  f16* B2f  = (f16*)alloc((size_t)128 * 512 * sizeof(f16));    // W2 f16
  f16* xw2h = (f16*)alloc((size_t)Mpad * 128 * sizeof(f16));   // layer2 pre-agg
  float* attWT = (float*)alloc((size_t)8 * 256 * sizeof(float));
  float* aS1 = (float*)alloc((size_t)N * 4 * sizeof(float));
  float* aD1 = (float*)alloc((size_t)N * 4 * sizeof(float));
  float* aS2 = (float*)alloc((size_t)N * sizeof(float));
  float* aD2 = (float*)alloc((size_t)N * sizeof(float));
  int* deg     = (int*)alloc((size_t)N * sizeof(int));
  int* row_ptr = (int*)alloc((size_t)(N + 1) * sizeof(int));
  int* cursor  = (int*)alloc((size_t)N * sizeof(int));
  int* csr     = (int*)alloc((size_t)EA * sizeof(int));
  int* tmp     = (int*)alloc((size_t)N * sizeof(int));
  int* bsum    = (int*)alloc((size_t)NB * sizeof(int));
  int* boff    = (int*)alloc((size_t)NB * sizeof(int));
  int* flag    = (int*)alloc(256);
  (void)n_in; (void)out_size; (void)ws_size;

  hipMemsetAsync(deg, 0, (size_t)N * sizeof(int), stream);
  if (Mpad > N)  // zero A2 pad rows so GEMM2 pad outputs stay finite
    hipMemsetAsync(A2 + (size_t)N * 512, 0, (size_t)(Mpad - N) * 512 * sizeof(f16), stream);

  detect_i64_kernel<<<1, 64, 0, stream>>>(ei, flag);
  hist_kernel<<<EB, 256, 0, stream>>>(ei, E, N, flag, deg);
  scan1_kernel<<<NB, 256, 0, stream>>>(deg, tmp, bsum, N);
  scan2_kernel<<<1, 256, 0, stream>>>(bsum, boff, NB);
  scan3_kernel<<<NB, 256, 0, stream>>>(deg, tmp, boff, row_ptr, cursor, N);
  scatter_kernel<<<EB, 256, 0, stream>>>(ei, E, N, flag, cursor, csr);

  attw_kernel<<<4, 256, 0, stream>>>(W1, att1s, att1d, attWT);
  cvtx_kernel<<<(N + 15) / 16, 256, 0, stream>>>(x, attWT, xf, aS1, aD1, N);
  cvt_f16_kernel<<<(512 * 64 + 255) / 256, 256, 0, stream>>>(W1, B1f, 512, 512, 256, 6);
  cvt_f16_kernel<<<(128 * 128 + 255) / 256, 256, 0, stream>>>(W2, B2f, 128, 128, 512, 7);

  agg1_kernel<<<(N + 3) / 4, 256, 0, stream>>>(row_ptr, csr, aS1, aD1, xf, aggX, N);
  dim3 g1(4, Mpad / 128);
  gemm1_kernel<<<g1, 256, 0, stream>>>(aggX, B1f, b1, A2, N);

  dim3 g2(1, Mpad / 64);
  gemm2_kernel<<<g2, 256, 0, stream>>>(A2, B2f, xw2h, att2s, att2d, aS2, aD2, 512, 128, N);
  agg2_kernel<<<(N + 3) / 4, 256, 0, stream>>>(row_ptr, csr, aS2, aD2, xw2h, b2, Wc, bc, out, N);
}